// Round 5
// baseline (355.355 us; speedup 1.0000x reference)
//
#include <hip/hip_runtime.h>

#define SEQ   1024
#define BATCH 512
#define NC    48
#define CH    8

typedef float f2 __attribute__((ext_vector_type(2)));
typedef float f4 __attribute__((ext_vector_type(4)));

__device__ __forceinline__ float rfl(float x) {
    return __int_as_float(__builtin_amdgcn_readfirstlane(__float_as_int(x)));
}
// packed fp32 FMA: acc.lo += a.lo*b.lo ; acc.hi += a.hi*b.hi  (proven R6/R9)
__device__ __forceinline__ void pkfma(f2& acc, f2 a, f2 b) {
    asm("v_pk_fma_f32 %0, %1, %2, %0" : "+v"(acc) : "v"(a), "v"(b));
}
#define LO2(Q) __builtin_shufflevector(Q, Q, 0, 1)
#define HI2(Q) __builtin_shufflevector(Q, Q, 2, 3)

// all-reduce across lane pairs {l, l^16} / {l, l^32} (proven correct in R8):
// feeding v into both operands makes out0+out1 == v[l] + v[l^K] on every lane.
__device__ __forceinline__ float xadd16(float v) {
    auto r = __builtin_amdgcn_permlane16_swap(__float_as_uint(v), __float_as_uint(v), false, false);
    return __uint_as_float(r[0]) + __uint_as_float(r[1]);
}
__device__ __forceinline__ float xadd32(float v) {
    auto r = __builtin_amdgcn_permlane32_swap(__float_as_uint(v), __float_as_uint(v), false, false);
    return __uint_as_float(r[0]) + __uint_as_float(r[1]);
}

// R10: shrink the per-step DS critical path (R9: 425 cy/step, ~350 of it the
// write + 12x ds_read_b128 broadcast roundtrip). Distribute the dot product:
// lane (p = lane>>4, q = lane&15) owns output cols {q,16+q,32+q} and input
// rows [12p,12p+12). Step = 1 ds_write + 3 ds_read_b128 (only its 12 z's;
// disjoint banks across p-groups, broadcast within) + 18 pkfma (3 cols x 6)
// + 3 hadds + p-reduce via permlane16/32_swap (12 ops) + 3 esm muls.
// esm staged in LDS per 8-step chunk (PRODUCE), value prefetched 1 step
// ahead in regs (off critical path). Exact pow2 rescale every 4 steps.
// All components individually correctness-proven in R6/R8/R9.
__global__ __launch_bounds__(64, 1) void crf_fwd(
    const float* __restrict__ scores,   // [SEQ][BATCH][NC]
    const int*   __restrict__ target,   // [SEQ][BATCH]
    const int*   __restrict__ lengths,  // [BATCH]
    const float* __restrict__ trans,    // [NC][NC]
    float* __restrict__ out)            // [2*BATCH]: X, then X - logZ
{
    const int b    = blockIdx.x;
    const int lane = threadIdx.x;
    const int q    = lane & 15;
    const int p    = lane >> 4;
    const int jc   = (lane < NC) ? lane : (NC - 1);
    const int L    = lengths[b];                       // uniform within block
    const float LOG2E = 1.4426950408889634f;
    const float LN2   = 0.6931471805599453f;
    const size_t TS = (size_t)BATCH * NC;
    const float* sp = scores + (size_t)b * NC + jc;

    __shared__ __align__(16) float zbuf[64];
    __shared__ __align__(16) float esmb[2][CH][NC];    // exp(s_t) staging

    // ---- raw score chunk staging (coalesced: lane jc owns column jc) ----
    float rA[CH], rB[CH];
    #define PREFETCH(buf, tbase) do { \
        _Pragma("unroll") \
        for (int k_ = 0; k_ < CH; ++k_) { \
            int tt_ = (tbase) + k_; if (tt_ > SEQ - 1) tt_ = SEQ - 1; \
            (buf)[k_] = sp[(size_t)tt_ * TS]; \
        } } while (0)
    PREFETCH(rA, 0);
    PREFETCH(rB, CH);

    // ---- target path score X (parallel over t, then reduce) ----
    float x = 0.f;
    #pragma unroll 4
    for (int t = lane; t < L; t += 64) {
        int cur = target[t * BATCH + b];
        float e = scores[(size_t)t * TS + (size_t)b * NC + cur];
        float tr = 0.f;
        if (t > 0) {
            int prev = target[(t - 1) * BATCH + b];
            tr = trans[prev * NC + cur];
        }
        x += e + tr;
    }
    #pragma unroll
    for (int k = 32; k >= 1; k >>= 1) x += __shfl_xor(x, k, 64);

    // ---- E tiles: EP[c][k] = {e^T[12p+2k][col_c], e^T[12p+2k+1][col_c]},
    //      col_0..2 = {q, 16+q, 32+q} ----
    f2 EP[3][6];
    #pragma unroll
    for (int c = 0; c < 3; ++c) {
        int col = 16*c + q;
        #pragma unroll
        for (int k = 0; k < 6; ++k) {
            EP[c][k].x = __builtin_amdgcn_exp2f(trans[(12*p + 2*k)*NC + col] * LOG2E);
            EP[c][k].y = __builtin_amdgcn_exp2f(trans[(12*p + 2*k + 1)*NC + col] * LOG2E);
            asm("" : "+v"(EP[c][k]));   // pin: no remat
        }
    }

    // ---- t = 0 init: v_c = z[col_c] = exp(s0[col_c] - s0[0]), replicated over p ----
    const float* s0p = scores + (size_t)b * NC;
    float i0 = s0p[q], i1 = s0p[16+q], i2 = s0p[32+q];
    float s00 = rfl(i0);                               // lane 0 holds s0[0]
    float v0 = __builtin_amdgcn_exp2f((i0 - s00) * LOG2E);
    float v1 = __builtin_amdgcn_exp2f((i1 - s00) * LOG2E);
    float v2 = __builtin_amdgcn_exp2f((i2 - s00) * LOG2E);
    float S  = s00 * LOG2E;

    // ---- esm production: one exp per lane per t into the chunk slot ----
    #define PRODUCE(slot, buf) do { if (lane < NC) { \
        _Pragma("unroll") \
        for (int j_ = 0; j_ < CH; ++j_) \
            esmb[slot][j_][jc] = __builtin_amdgcn_exp2f((buf)[j_] * LOG2E); \
        } } while (0)
    PRODUCE(0, rA);

    float emA0, emA1, emA2, emB0, emB1, emB2;   // esm double buffer (by step parity)
    #define LOADEM(e0, e1, e2, t_) do { \
        const float* er_ = &esmb[((t_) >> 3) & 1][(t_) & 7][0]; \
        e0 = er_[q]; e1 = er_[16+q]; e2 = er_[32+q]; } while (0)

    // exact pow2 rescale (logZ-invariant, safe on frozen lanes): every 4 steps
    #define RS() do { \
        int eb_ = (__builtin_amdgcn_readfirstlane(__float_as_int(v0)) >> 23) & 255; \
        float sc_ = __int_as_float((254 - eb_) << 23); \
        v0 *= sc_; v1 *= sc_; v2 *= sc_; S += (float)(eb_ - 127); \
    } while (0)

    // one step: distributed broadcast + packed MACs + permlane p-reduce
    #define STEP_CORE(em0, em1, em2, en0, en1, en2, tnext, ZUPD) do { \
        float vw_ = v0; if (p == 1) vw_ = v1; if (p == 2) vw_ = v2; \
        zbuf[lane] = vw_;                 /* zbuf[j]=z[j] for j<48; 48-63 dummy */ \
        asm volatile("" ::: "memory");    /* keep reads after the write */ \
        const f4* zq_ = (const f4*)(zbuf + 12*p); \
        f4 Z0 = zq_[0], Z1 = zq_[1], Z2 = zq_[2]; \
        LOADEM(en0, en1, en2, tnext);     /* next step's esm, off-path */ \
        f2 a0 = LO2(Z0)*EP[0][0], a1 = LO2(Z0)*EP[1][0], a2 = LO2(Z0)*EP[2][0]; \
        pkfma(a0, HI2(Z0), EP[0][1]); pkfma(a1, HI2(Z0), EP[1][1]); pkfma(a2, HI2(Z0), EP[2][1]); \
        pkfma(a0, LO2(Z1), EP[0][2]); pkfma(a1, LO2(Z1), EP[1][2]); pkfma(a2, LO2(Z1), EP[2][2]); \
        pkfma(a0, HI2(Z1), EP[0][3]); pkfma(a1, HI2(Z1), EP[1][3]); pkfma(a2, HI2(Z1), EP[2][3]); \
        pkfma(a0, LO2(Z2), EP[0][4]); pkfma(a1, LO2(Z2), EP[1][4]); pkfma(a2, LO2(Z2), EP[2][4]); \
        pkfma(a0, HI2(Z2), EP[0][5]); pkfma(a1, HI2(Z2), EP[1][5]); pkfma(a2, HI2(Z2), EP[2][5]); \
        float s0_ = a0.x + a0.y, s1_ = a1.x + a1.y, s2_ = a2.x + a2.y; \
        s0_ = xadd16(s0_); s1_ = xadd16(s1_); s2_ = xadd16(s2_); \
        s0_ = xadd32(s0_); s1_ = xadd32(s1_); s2_ = xadd32(s2_); \
        float nv0_ = s0_ * (em0), nv1_ = s1_ * (em1), nv2_ = s2_ * (em2); \
        ZUPD; \
    } while (0)

    // parity convention: odd steps use emA (load emB), even use emB (load emA)
    #define STEPA_U(t_) STEP_CORE(emA0,emA1,emA2, emB0,emB1,emB2, (t_)+1, { v0=nv0_; v1=nv1_; v2=nv2_; })
    #define STEPB_U(t_) STEP_CORE(emB0,emB1,emB2, emA0,emA1,emA2, (t_)+1, { v0=nv0_; v1=nv1_; v2=nv2_; })
    #define STEPA_G(t_) STEP_CORE(emA0,emA1,emA2, emB0,emB1,emB2, (t_)+1, { if ((t_) < L) { v0=nv0_; v1=nv1_; v2=nv2_; } })
    #define STEPB_G(t_) STEP_CORE(emB0,emB1,emB2, emA0,emA1,emA2, (t_)+1, { if ((t_) < L) { v0=nv0_; v1=nv1_; v2=nv2_; } })

    // prologue: steps 1..7 from chunk 0 (guarded; L may be small)
    LOADEM(emA0, emA1, emA2, 1);
    STEPA_G(1); STEPB_G(2); STEPA_G(3); RS();
    STEPB_G(4); STEPA_G(5); STEPB_G(6); STEPA_G(7); RS();

    // main: unguarded full chunks [t0, t0+8). At iteration top: produce this
    // chunk's esm slot (raw chunk prefetched earlier), prefetch chunk k+2 into
    // the freed buffer, reload em for step t0 (its in-chunk prefetch preceded
    // this PRODUCE and read a stale slot).
    int t0 = CH;
    while (t0 + CH <= L) {
        int k_ = t0 >> 3;
        if (k_ & 1) { PRODUCE(1, rB); PREFETCH(rB, t0 + 2*CH); }
        else        { PRODUCE(0, rA); PREFETCH(rA, t0 + 2*CH); }
        LOADEM(emB0, emB1, emB2, t0);
        STEPB_U(t0);   STEPA_U(t0+1); STEPB_U(t0+2); STEPA_U(t0+3); RS();
        STEPB_U(t0+4); STEPA_U(t0+5); STEPB_U(t0+6); STEPA_U(t0+7); RS();
        t0 += CH;
    }
    // guarded tail chunk (steps t0 .. L-1; its esm slot not yet produced)
    if (t0 < L) {
        int k_ = t0 >> 3;
        if (k_ & 1) PRODUCE(1, rB); else PRODUCE(0, rA);
        LOADEM(emB0, emB1, emB2, t0);
        STEPB_G(t0);   STEPA_G(t0+1); STEPB_G(t0+2); STEPA_G(t0+3); RS();
        STEPB_G(t0+4); STEPA_G(t0+5); STEPB_G(t0+6);
    }

    #undef STEP_CORE
    #undef STEPA_U
    #undef STEPB_U
    #undef STEPA_G
    #undef STEPB_G
    #undef RS
    #undef LOADEM
    #undef PRODUCE
    #undef PREFETCH

    // ---- finalize: each 16-lane row holds all 48 cols (replicated over p):
    //      Z = v0+v1+v2 summed over q ----
    float zs = v0 + v1 + v2;
    zs += __shfl_xor(zs, 1, 64);
    zs += __shfl_xor(zs, 2, 64);
    zs += __shfl_xor(zs, 4, 64);
    zs += __shfl_xor(zs, 8, 64);
    float logZ = (__builtin_amdgcn_logf(zs) + S) * LN2;

    if (lane == 0) {
        out[b]         = x;          // output 0: X
        out[BATCH + b] = x - logZ;   // output 1: X - logZ
    }
}

extern "C" void kernel_launch(void* const* d_in, const int* in_sizes, int n_in,
                              void* d_out, int out_size, void* d_ws, size_t ws_size,
                              hipStream_t stream) {
    const float* scores  = (const float*)d_in[0];
    const int*   target  = (const int*)d_in[1];
    const int*   lengths = (const int*)d_in[2];
    const float* trans   = (const float*)d_in[3];
    float* out = (float*)d_out;
    crf_fwd<<<BATCH, 64, 0, stream>>>(scores, target, lengths, trans, out);
}

// Round 6
// 282.556 us; speedup vs baseline: 1.2576x; 1.2576x over previous
//
#include <hip/hip_runtime.h>

#define SEQ   1024
#define BATCH 512
#define NC    48
#define CH    8

typedef float f2 __attribute__((ext_vector_type(2)));
typedef float f4 __attribute__((ext_vector_type(4)));

__device__ __forceinline__ float rfl(float x) {
    return __int_as_float(__builtin_amdgcn_readfirstlane(__float_as_int(x)));
}
// packed fp32 FMA: acc.lo += a.lo*b.lo ; acc.hi += a.hi*b.hi  (proven R6/R9)
__device__ __forceinline__ void pkfma(f2& acc, f2 a, f2 b) {
    asm("v_pk_fma_f32 %0, %1, %2, %0" : "+v"(acc) : "v"(a), "v"(b));
}
#define LO2(Q) __builtin_shufflevector(Q, Q, 0, 1)
#define HI2(Q) __builtin_shufflevector(Q, Q, 2, 3)

// R11: two independent chains per wave (split the serial recurrence).
//   logZ = log( 1^T (prod_{t=1}^{L-1} A_t) z_0 ),  A_t = D_t E^T (frozen A_t = I for t>=L).
// Split at M=512:  forward  z_t = D_t E^T z_{t-1}        for t = 1..511
//                  backward u_t = E D_t u_{t+1}, u_1024=1 for t = 1023..512
//   logZ = log( u_512^T z_511 )   (exact; for L<=512 u stays all-ones).
// The two chains are independent -> interleaving one step of each hides the
// ~175cy LDS write->read turnaround (R9's exposed latency) under the other
// chain's MAC issue. Per pair-step: 2 ds_write + 24 ds_read_b128 + 48 pkfma.
// Step mechanics identical to R9 (proven): LDS all-broadcast + packed MACs,
// esm in registers via per-chunk EXP8, exact pow2 rescale every 4 steps.
__global__ __launch_bounds__(64, 1) void crf_fwd(
    const float* __restrict__ scores,   // [SEQ][BATCH][NC]
    const int*   __restrict__ target,   // [SEQ][BATCH]
    const int*   __restrict__ lengths,  // [BATCH]
    const float* __restrict__ trans,    // [NC][NC]
    float* __restrict__ out)            // [2*BATCH]: X, then X - logZ
{
    const int b    = blockIdx.x;
    const int lane = threadIdx.x;
    const int jc   = (lane < NC) ? lane : (NC - 1);   // lanes 48-63 mirror idx 47 (excluded at reduce)
    const int L    = lengths[b];                       // uniform within block
    const float LOG2E = 1.4426950408889634f;
    const float LN2   = 0.6931471805599453f;
    const size_t TS = (size_t)BATCH * NC;
    const float* sp = scores + (size_t)b * NC + jc;

    __shared__ __align__(16) float zbF[64];
    __shared__ __align__(16) float zbB[64];

    // ---- raw score chunk buffers, addressed by CHUNK index (t = 8*ck+j) ----
    float fA[CH], fB[CH], bA[CH], bB[CH];
    #define PREFETCH(buf, ck) do { \
        _Pragma("unroll") \
        for (int j_ = 0; j_ < CH; ++j_) \
            (buf)[j_] = sp[(size_t)((ck)*CH + j_) * TS]; \
        } while (0)
    PREFETCH(fA, 0); PREFETCH(fB, 1);        // fwd chunks 0,1
    PREFETCH(bA, 127); PREFETCH(bB, 126);    // bwd chunks 127,126

    // ---- target path score X (parallel over t, then reduce) ----
    float x = 0.f;
    #pragma unroll 4
    for (int t = lane; t < L; t += 64) {
        int cur = target[t * BATCH + b];
        float e = scores[(size_t)t * TS + (size_t)b * NC + cur];
        float tr = 0.f;
        if (t > 0) {
            int prev = target[(t - 1) * BATCH + b];
            tr = trans[prev * NC + cur];
        }
        x += e + tr;
    }
    #pragma unroll
    for (int k = 32; k >= 1; k >>= 1) x += __shfl_xor(x, k, 64);

    // ---- E tiles (pinned in VGPRs):
    //   fwd: epF[k] = {e^T[2k][jc],   e^T[2k+1][jc]}   (column jc)
    //   bwd: epB[k] = {e^T[jc][2k],   e^T[jc][2k+1]}   (row jc)
    f2 epF[24], epB[24];
    #pragma unroll
    for (int k = 0; k < 24; ++k) {
        epF[k].x = __builtin_amdgcn_exp2f(trans[(2*k)*NC + jc] * LOG2E);
        epF[k].y = __builtin_amdgcn_exp2f(trans[(2*k+1)*NC + jc] * LOG2E);
        asm("" : "+v"(epF[k]));
        epB[k].x = __builtin_amdgcn_exp2f(trans[jc*NC + 2*k] * LOG2E);
        epB[k].y = __builtin_amdgcn_exp2f(trans[jc*NC + 2*k + 1] * LOG2E);
        asm("" : "+v"(epB[k]));
    }

    // ---- chain states ----
    float sv_init = fA[0];                    // raw s_0[jc]
    float s00 = rfl(sv_init);                 // s_0[0]
    float z  = __builtin_amdgcn_exp2f((sv_init - s00) * LOG2E);
    float SF = s00 * LOG2E;
    float u  = 1.f;
    float SB = 0.f;

    #define EXP8(buf) do { _Pragma("unroll") \
        for (int k_ = 0; k_ < CH; ++k_) (buf)[k_] = __builtin_amdgcn_exp2f((buf)[k_] * LOG2E); } while (0)

    // exact pow2 rescale (logZ-invariant, safe on frozen chains)
    #define RSF() do { \
        int e_ = (__builtin_amdgcn_readfirstlane(__float_as_int(z)) >> 23) & 255; \
        z *= __int_as_float((254 - e_) << 23); SF += (float)(e_ - 127); } while (0)
    #define RSB() do { \
        int e_ = (__builtin_amdgcn_readfirstlane(__float_as_int(u)) >> 23) & 255; \
        u *= __int_as_float((254 - e_) << 23); SB += (float)(e_ - 127); } while (0)

    // matvec cores (zbF/zbB written + clobber issued by caller); 2 accs each
    #define FWD_MV(fesm, ZN) \
        const f4* fq_ = (const f4*)zbF; \
        f4 F0=fq_[0],F1=fq_[1],F2=fq_[2],F3=fq_[3],F4=fq_[4],F5=fq_[5]; \
        f4 F6=fq_[6],F7=fq_[7],F8=fq_[8],F9=fq_[9],F10=fq_[10],F11=fq_[11]; \
        f2 x0_ = LO2(F0)*epF[0],  x1_ = HI2(F0)*epF[1]; \
        pkfma(x0_, LO2(F1),  epF[2]);  pkfma(x1_, HI2(F1),  epF[3]); \
        pkfma(x0_, LO2(F2),  epF[4]);  pkfma(x1_, HI2(F2),  epF[5]); \
        pkfma(x0_, LO2(F3),  epF[6]);  pkfma(x1_, HI2(F3),  epF[7]); \
        pkfma(x0_, LO2(F4),  epF[8]);  pkfma(x1_, HI2(F4),  epF[9]); \
        pkfma(x0_, LO2(F5),  epF[10]); pkfma(x1_, HI2(F5),  epF[11]); \
        pkfma(x0_, LO2(F6),  epF[12]); pkfma(x1_, HI2(F6),  epF[13]); \
        pkfma(x0_, LO2(F7),  epF[14]); pkfma(x1_, HI2(F7),  epF[15]); \
        pkfma(x0_, LO2(F8),  epF[16]); pkfma(x1_, HI2(F8),  epF[17]); \
        pkfma(x0_, LO2(F9),  epF[18]); pkfma(x1_, HI2(F9),  epF[19]); \
        pkfma(x0_, LO2(F10), epF[20]); pkfma(x1_, HI2(F10), epF[21]); \
        pkfma(x0_, LO2(F11), epF[22]); pkfma(x1_, HI2(F11), epF[23]); \
        f2 xs_ = x0_ + x1_; \
        float ZN = (xs_.x + xs_.y) * (fesm);
    #define BWD_MV(UN) \
        const f4* bq_ = (const f4*)zbB; \
        f4 B0=bq_[0],B1=bq_[1],B2=bq_[2],B3=bq_[3],B4=bq_[4],B5=bq_[5]; \
        f4 B6=bq_[6],B7=bq_[7],B8=bq_[8],B9=bq_[9],B10=bq_[10],B11=bq_[11]; \
        f2 y0_ = LO2(B0)*epB[0],  y1_ = HI2(B0)*epB[1]; \
        pkfma(y0_, LO2(B1),  epB[2]);  pkfma(y1_, HI2(B1),  epB[3]); \
        pkfma(y0_, LO2(B2),  epB[4]);  pkfma(y1_, HI2(B2),  epB[5]); \
        pkfma(y0_, LO2(B3),  epB[6]);  pkfma(y1_, HI2(B3),  epB[7]); \
        pkfma(y0_, LO2(B4),  epB[8]);  pkfma(y1_, HI2(B4),  epB[9]); \
        pkfma(y0_, LO2(B5),  epB[10]); pkfma(y1_, HI2(B5),  epB[11]); \
        pkfma(y0_, LO2(B6),  epB[12]); pkfma(y1_, HI2(B6),  epB[13]); \
        pkfma(y0_, LO2(B7),  epB[14]); pkfma(y1_, HI2(B7),  epB[15]); \
        pkfma(y0_, LO2(B8),  epB[16]); pkfma(y1_, HI2(B8),  epB[17]); \
        pkfma(y0_, LO2(B9),  epB[18]); pkfma(y1_, HI2(B9),  epB[19]); \
        pkfma(y0_, LO2(B10), epB[20]); pkfma(y1_, HI2(B10), epB[21]); \
        pkfma(y0_, LO2(B11), epB[22]); pkfma(y1_, HI2(B11), epB[23]); \
        f2 ys_ = y0_ + y1_; \
        float UN = ys_.x + ys_.y;

    // interleaved pair-step (both chains, unguarded)
    #define STEP2_U(fesm, besm) do { \
        zbF[lane] = z; \
        float vw_ = u * (besm); \
        zbB[lane] = vw_; \
        asm volatile("" ::: "memory"); \
        FWD_MV(fesm, zn_) \
        BWD_MV(un_) \
        z = zn_; u = un_; \
    } while (0)

    // solo steps
    #define STEPF_U(fesm) do { \
        zbF[lane] = z; asm volatile("" ::: "memory"); \
        FWD_MV(fesm, zn_) z = zn_; } while (0)
    #define STEPF_G(fesm, t_) do { \
        zbF[lane] = z; asm volatile("" ::: "memory"); \
        FWD_MV(fesm, zn_) if ((t_) < L) z = zn_; } while (0)
    #define STEPB_G(besm, t_) do { \
        float vw_ = u * (besm); zbB[lane] = vw_; \
        asm volatile("" ::: "memory"); \
        BWD_MV(un_) if ((t_) < L) u = un_; } while (0)

    // ---- iteration 0 (special: fwd steps 1..7 guarded; bwd chunk 127 guarded) ----
    EXP8(fA);
    STEPF_G(fA[1],1); STEPF_G(fA[2],2); STEPF_G(fA[3],3); RSF();
    STEPF_G(fA[4],4); STEPF_G(fA[5],5); STEPF_G(fA[6],6); STEPF_G(fA[7],7); RSF();
    if (1016 < L) {
        EXP8(bA);
        STEPB_G(bA[7],1023); STEPB_G(bA[6],1022); STEPB_G(bA[5],1021); STEPB_G(bA[4],1020); RSB();
        STEPB_G(bA[3],1019); STEPB_G(bA[2],1018); STEPB_G(bA[1],1017); STEPB_G(bA[0],1016); RSB();
    }
    PREFETCH(fA, 2); PREFETCH(bA, 125);

    // ---- main loop: it = 1..63; buffer(it&1) holds fwd chunk it / bwd chunk 127-it ----
    #define ITER(fb, bb, it_) do { \
        const int cb_ = 127 - (it_); \
        const int ft_ = CH * (it_); \
        const int bt_ = CH * cb_; \
        if (ft_ + CH <= L && bt_ + CH - 1 < L) {            /* both fully active */ \
            EXP8(fb); EXP8(bb); \
            STEP2_U((fb)[0],(bb)[7]); STEP2_U((fb)[1],(bb)[6]); \
            STEP2_U((fb)[2],(bb)[5]); STEP2_U((fb)[3],(bb)[4]); RSF(); RSB(); \
            STEP2_U((fb)[4],(bb)[3]); STEP2_U((fb)[5],(bb)[2]); \
            STEP2_U((fb)[6],(bb)[1]); STEP2_U((fb)[7],(bb)[0]); RSF(); RSB(); \
        } else if (ft_ + CH <= L && bt_ >= L) {             /* fwd solo, bwd frozen */ \
            EXP8(fb); \
            STEPF_U((fb)[0]); STEPF_U((fb)[1]); STEPF_U((fb)[2]); STEPF_U((fb)[3]); RSF(); \
            STEPF_U((fb)[4]); STEPF_U((fb)[5]); STEPF_U((fb)[6]); STEPF_U((fb)[7]); RSF(); \
        } else {                                            /* boundary chunks: guarded */ \
            if (ft_ < L) { \
                EXP8(fb); \
                STEPF_G((fb)[0],ft_+0); STEPF_G((fb)[1],ft_+1); \
                STEPF_G((fb)[2],ft_+2); STEPF_G((fb)[3],ft_+3); RSF(); \
                STEPF_G((fb)[4],ft_+4); STEPF_G((fb)[5],ft_+5); \
                STEPF_G((fb)[6],ft_+6); STEPF_G((fb)[7],ft_+7); RSF(); \
            } \
            if (bt_ < L) { \
                EXP8(bb); \
                STEPB_G((bb)[7],bt_+7); STEPB_G((bb)[6],bt_+6); \
                STEPB_G((bb)[5],bt_+5); STEPB_G((bb)[4],bt_+4); RSB(); \
                STEPB_G((bb)[3],bt_+3); STEPB_G((bb)[2],bt_+2); \
                STEPB_G((bb)[1],bt_+1); STEPB_G((bb)[0],bt_+0); RSB(); \
            } \
        } \
        PREFETCH(fb, (it_) + 2);     /* chunk <= 65: valid memory, used iff needed */ \
        PREFETCH(bb, cb_ - 2);       /* chunk >= 62 */ \
    } while (0)

    #pragma unroll 1
    for (int it = 1; it < 64; ++it) {
        if (it & 1) { ITER(fB, bB, it); }
        else        { ITER(fA, bA, it); }
    }

    #undef ITER
    #undef STEP2_U
    #undef STEPF_U
    #undef STEPF_G
    #undef STEPB_G
    #undef FWD_MV
    #undef BWD_MV
    #undef RSF
    #undef RSB
    #undef EXP8
    #undef PREFETCH

    // ---- finalize: logZ = ln2 * (log2( sum_j z[j]*u[j] ) + SF + SB) ----
    float prod = (lane < NC) ? z * u : 0.f;
    #pragma unroll
    for (int k = 32; k >= 1; k >>= 1) prod += __shfl_xor(prod, k, 64);
    float logZ = (__builtin_amdgcn_logf(prod) + SF + SB) * LN2;

    if (lane == 0) {
        out[b]         = x;          // output 0: X
        out[BATCH + b] = x - logZ;   // output 1: X - logZ
    }
}

extern "C" void kernel_launch(void* const* d_in, const int* in_sizes, int n_in,
                              void* d_out, int out_size, void* d_ws, size_t ws_size,
                              hipStream_t stream) {
    const float* scores  = (const float*)d_in[0];
    const int*   target  = (const int*)d_in[1];
    const int*   lengths = (const int*)d_in[2];
    const float* trans   = (const float*)d_in[3];
    float* out = (float*)d_out;
    crf_fwd<<<BATCH, 64, 0, stream>>>(scores, target, lengths, trans, out);
}

// Round 7
// 239.613 us; speedup vs baseline: 1.4830x; 1.1792x over previous
//
#include <hip/hip_runtime.h>

#define SEQ   1024
#define BATCH 512
#define NC    48
#define CH    8

typedef float f2 __attribute__((ext_vector_type(2)));
typedef float f4 __attribute__((ext_vector_type(4)));

__device__ __forceinline__ float rfl(float x) {
    return __int_as_float(__builtin_amdgcn_readfirstlane(__float_as_int(x)));
}
// packed fp32 FMA: acc.lo += a.lo*b.lo ; acc.hi += a.hi*b.hi  (proven R6/R9/R11)
__device__ __forceinline__ void pkfma(f2& acc, f2 a, f2 b) {
    asm("v_pk_fma_f32 %0, %1, %2, %0" : "+v"(acc) : "v"(a), "v"(b));
}
#define LO2(Q) __builtin_shufflevector(Q, Q, 0, 1)
#define HI2(Q) __builtin_shufflevector(Q, Q, 2, 3)

// R12: split the chain ACROSS WAVES, not within one (R11 lesson: a lone wave
// is issue-bound ~ 20cy/DS-op + 5cy/VALU-op; two chains in ONE wave = exactly
// 2x the time; the machine was half idle at 512 waves / 1024 SIMDs).
//   logZ = log( 1^T (prod A_t) z_0 ),  A_t = D_t E^T  (A_t = I for t >= L)
//   wave 0: forward  z_t = D_t E^T z_{t-1},  t = 1..511      (R9 step, proven)
//   wave 1: backward u_t = E D_t u_{t+1},    t = 1023..512, u_1024 = 1
//   combine: logZ = log2( u_512 . z_511 ) + SF + SB   (exact; R11-verified math)
// Each wave runs the proven 425cy/step R9 solo structure on its own SIMD ->
// wall time per block halves. Backward wave skips fully-frozen chunks
// (uniform L per block), so L<=512 blocks degenerate to R9 exactly (u = 1).
__global__ __launch_bounds__(128, 1) void crf_fwd(
    const float* __restrict__ scores,   // [SEQ][BATCH][NC]
    const int*   __restrict__ target,   // [SEQ][BATCH]
    const int*   __restrict__ lengths,  // [BATCH]
    const float* __restrict__ trans,    // [NC][NC]
    float* __restrict__ out)            // [2*BATCH]: X, then X - logZ
{
    const int b    = blockIdx.x;
    const int tid  = threadIdx.x;
    const int lane = tid & 63;
    const int wid  = tid >> 6;
    const int jc   = (lane < NC) ? lane : (NC - 1);   // lanes 48-63 mirror idx 47 (excluded at reduce)
    const int L    = lengths[b];                       // uniform within block
    const float LOG2E = 1.4426950408889634f;
    const float LN2   = 0.6931471805599453f;
    const size_t TS = (size_t)BATCH * NC;
    const float* sp = scores + (size_t)b * NC + jc;

    __shared__ __align__(16) float zbF[64];   // wave 0 broadcast buffer
    __shared__ __align__(16) float zbB[64];   // wave 1 broadcast buffer
    __shared__ float ures[64];                // wave1 -> wave0 handoff
    __shared__ float xpart[2];
    __shared__ float shSB;

    #define PREFETCH(buf, tbase) do { \
        _Pragma("unroll") \
        for (int j_ = 0; j_ < CH; ++j_) { \
            int tt_ = (tbase) + j_; if (tt_ > SEQ - 1) tt_ = SEQ - 1; \
            (buf)[j_] = sp[(size_t)tt_ * TS]; \
        } } while (0)
    #define EXP8(buf) do { _Pragma("unroll") \
        for (int k_ = 0; k_ < CH; ++k_) (buf)[k_] = __builtin_amdgcn_exp2f((buf)[k_] * LOG2E); } while (0)

    // ---- target path score X (parallel over t across 128 threads) ----
    float x = 0.f;
    #pragma unroll 2
    for (int t = tid; t < L; t += 128) {
        int cur = target[t * BATCH + b];
        float e = scores[(size_t)t * TS + (size_t)b * NC + cur];
        float tr = 0.f;
        if (t > 0) {
            int prev = target[(t - 1) * BATCH + b];
            tr = trans[prev * NC + cur];
        }
        x += e + tr;
    }
    #pragma unroll
    for (int k = 32; k >= 1; k >>= 1) x += __shfl_xor(x, k, 64);
    if (lane == 0) xpart[wid] = x;

    float z = 0.f, SF = 0.f;   // wave 0 results (read after barrier)

    if (wid == 0) {
        // ================= forward chain: R9 verbatim, bounded at t=511 =====
        float fA[CH], fB[CH];
        PREFETCH(fA, 0); PREFETCH(fB, CH);
        f2 ep[24];                      // ep[k] = {e^T[2k][jc], e^T[2k+1][jc]}
        #pragma unroll
        for (int k = 0; k < 24; ++k) {
            ep[k].x = __builtin_amdgcn_exp2f(trans[(2*k)*NC + jc] * LOG2E);
            ep[k].y = __builtin_amdgcn_exp2f(trans[(2*k+1)*NC + jc] * LOG2E);
            asm("" : "+v"(ep[k]));      // pin: no remat
        }
        float sv = fA[0];
        float s00 = rfl(sv);
        z  = __builtin_amdgcn_exp2f((sv - s00) * LOG2E);
        SF = s00 * LOG2E;
        EXP8(fA);

        #define RSF() do { \
            int e_ = (__builtin_amdgcn_readfirstlane(__float_as_int(z)) >> 23) & 255; \
            z *= __int_as_float((254 - e_) << 23); SF += (float)(e_ - 127); } while (0)

        #define FSTEP_CORE(esmv, ZUPD) do { \
            zbF[lane] = z; \
            asm volatile("" ::: "memory"); \
            const f4* zq_ = (const f4*)zbF; \
            f4 Q0=zq_[0], Q1=zq_[1], Q2=zq_[2],  Q3=zq_[3]; \
            f4 Q4=zq_[4], Q5=zq_[5], Q6=zq_[6],  Q7=zq_[7]; \
            f4 Q8=zq_[8], Q9=zq_[9], Q10=zq_[10], Q11=zq_[11]; \
            f2 k0 = LO2(Q0)*ep[0],  k1 = HI2(Q0)*ep[1]; \
            f2 k2 = LO2(Q1)*ep[2],  k3 = HI2(Q1)*ep[3]; \
            pkfma(k0, LO2(Q2),  ep[4]);   pkfma(k1, HI2(Q2),  ep[5]); \
            pkfma(k2, LO2(Q3),  ep[6]);   pkfma(k3, HI2(Q3),  ep[7]); \
            pkfma(k0, LO2(Q4),  ep[8]);   pkfma(k1, HI2(Q4),  ep[9]); \
            pkfma(k2, LO2(Q5),  ep[10]);  pkfma(k3, HI2(Q5),  ep[11]); \
            pkfma(k0, LO2(Q6),  ep[12]);  pkfma(k1, HI2(Q6),  ep[13]); \
            pkfma(k2, LO2(Q7),  ep[14]);  pkfma(k3, HI2(Q7),  ep[15]); \
            pkfma(k0, LO2(Q8),  ep[16]);  pkfma(k1, HI2(Q8),  ep[17]); \
            pkfma(k2, LO2(Q9),  ep[18]);  pkfma(k3, HI2(Q9),  ep[19]); \
            pkfma(k0, LO2(Q10), ep[20]);  pkfma(k1, HI2(Q10), ep[21]); \
            pkfma(k2, LO2(Q11), ep[22]);  pkfma(k3, HI2(Q11), ep[23]); \
            f2 kk = (k0 + k1) + (k2 + k3); \
            float znew_ = (kk.x + kk.y) * (esmv); \
            ZUPD; \
        } while (0)
        #define FSTEPU(buf, i)      FSTEP_CORE((buf)[i], z = znew_)
        #define FSTEPG(buf, i, tb)  FSTEP_CORE((buf)[i], if (((tb)+(i)) < L) z = znew_)
        #define FCHUNK8U(buf) do { \
            FSTEPU(buf,0); FSTEPU(buf,1); FSTEPU(buf,2); FSTEPU(buf,3); RSF(); \
            FSTEPU(buf,4); FSTEPU(buf,5); FSTEPU(buf,6); FSTEPU(buf,7); RSF(); } while (0)
        #define FCHUNK8G(buf, tb) do { \
            FSTEPG(buf,0,tb); FSTEPG(buf,1,tb); FSTEPG(buf,2,tb); FSTEPG(buf,3,tb); RSF(); \
            FSTEPG(buf,4,tb); FSTEPG(buf,5,tb); FSTEPG(buf,6,tb); FSTEPG(buf,7,tb); RSF(); } while (0)

        // prologue: steps 1..7 (guarded; L may be small)
        FSTEPG(fA,1,0); FSTEPG(fA,2,0); FSTEPG(fA,3,0); RSF();
        FSTEPG(fA,4,0); FSTEPG(fA,5,0); FSTEPG(fA,6,0); FSTEPG(fA,7,0); RSF();

        const int Lf = (L < 512) ? L : 512;   // forward stops at z_511
        int t0 = CH;
        int useB = 1;
        while (t0 + CH <= Lf) {
            if (useB) { PREFETCH(fA, t0 + CH); EXP8(fB); FCHUNK8U(fB); }
            else      { PREFETCH(fB, t0 + CH); EXP8(fA); FCHUNK8U(fA); }
            useB ^= 1;
            t0 += CH;
        }
        if (t0 < Lf) {
            if (useB) { EXP8(fB); FCHUNK8G(fB, t0); }
            else      { EXP8(fA); FCHUNK8G(fA, t0); }
        }
    } else {
        // ================= backward chain: u_t = E (esm_t * u_{t+1}) ========
        float bA[CH], bB[CH];
        f2 eb[24];                      // eb[k] = {e^T[jc][2k], e^T[jc][2k+1]}  (row jc)
        #pragma unroll
        for (int k = 0; k < 24; ++k) {
            eb[k].x = __builtin_amdgcn_exp2f(trans[jc*NC + 2*k] * LOG2E);
            eb[k].y = __builtin_amdgcn_exp2f(trans[jc*NC + 2*k + 1] * LOG2E);
            asm("" : "+v"(eb[k]));
        }
        float u = 1.f, SB = 0.f;

        #define RSB() do { \
            int e_ = (__builtin_amdgcn_readfirstlane(__float_as_int(u)) >> 23) & 255; \
            u *= __int_as_float((254 - e_) << 23); SB += (float)(e_ - 127); } while (0)

        #define BSTEP_CORE(esmv, UUPD) do { \
            float vw_ = u * (esmv); \
            zbB[lane] = vw_; \
            asm volatile("" ::: "memory"); \
            const f4* bq_ = (const f4*)zbB; \
            f4 Q0=bq_[0], Q1=bq_[1], Q2=bq_[2],  Q3=bq_[3]; \
            f4 Q4=bq_[4], Q5=bq_[5], Q6=bq_[6],  Q7=bq_[7]; \
            f4 Q8=bq_[8], Q9=bq_[9], Q10=bq_[10], Q11=bq_[11]; \
            f2 k0 = LO2(Q0)*eb[0],  k1 = HI2(Q0)*eb[1]; \
            f2 k2 = LO2(Q1)*eb[2],  k3 = HI2(Q1)*eb[3]; \
            pkfma(k0, LO2(Q2),  eb[4]);   pkfma(k1, HI2(Q2),  eb[5]); \
            pkfma(k2, LO2(Q3),  eb[6]);   pkfma(k3, HI2(Q3),  eb[7]); \
            pkfma(k0, LO2(Q4),  eb[8]);   pkfma(k1, HI2(Q4),  eb[9]); \
            pkfma(k2, LO2(Q5),  eb[10]);  pkfma(k3, HI2(Q5),  eb[11]); \
            pkfma(k0, LO2(Q6),  eb[12]);  pkfma(k1, HI2(Q6),  eb[13]); \
            pkfma(k2, LO2(Q7),  eb[14]);  pkfma(k3, HI2(Q7),  eb[15]); \
            pkfma(k0, LO2(Q8),  eb[16]);  pkfma(k1, HI2(Q8),  eb[17]); \
            pkfma(k2, LO2(Q9),  eb[18]);  pkfma(k3, HI2(Q9),  eb[19]); \
            pkfma(k0, LO2(Q10), eb[20]);  pkfma(k1, HI2(Q10), eb[21]); \
            pkfma(k2, LO2(Q11), eb[22]);  pkfma(k3, HI2(Q11), eb[23]); \
            f2 kk = (k0 + k1) + (k2 + k3); \
            float unew_ = kk.x + kk.y; \
            UUPD; \
        } while (0)
        #define BSTEPU(buf, i)      BSTEP_CORE((buf)[i], u = unew_)
        #define BSTEPG(buf, i, tb)  BSTEP_CORE((buf)[i], if (((tb)+(i)) < L) u = unew_)
        #define BCHUNK8U(buf) do { \
            BSTEPU(buf,7); BSTEPU(buf,6); BSTEPU(buf,5); BSTEPU(buf,4); RSB(); \
            BSTEPU(buf,3); BSTEPU(buf,2); BSTEPU(buf,1); BSTEPU(buf,0); RSB(); } while (0)

        if (L > 512) {                       // else: u stays 1 exactly
            const int chi = (L - 1) >> 3;    // top active chunk, in [64,127]
            const int tbt = chi * CH;
            PREFETCH(bA, tbt); PREFETCH(bB, tbt - CH);
            EXP8(bA);
            // top chunk guarded (t >= L frozen), steps descend
            BSTEPG(bA,7,tbt); BSTEPG(bA,6,tbt); BSTEPG(bA,5,tbt); BSTEPG(bA,4,tbt); RSB();
            BSTEPG(bA,3,tbt); BSTEPG(bA,2,tbt); BSTEPG(bA,1,tbt); BSTEPG(bA,0,tbt); RSB();
            PREFETCH(bA, tbt - 2*CH);
            int ck = chi - 1;
            int useB2 = 1;
            while (ck >= 64) {               // unguarded full chunks down to t=512
                if (useB2) { EXP8(bB); BCHUNK8U(bB); PREFETCH(bB, (ck-2)*CH); }
                else       { EXP8(bA); BCHUNK8U(bA); PREFETCH(bA, (ck-2)*CH); }
                useB2 ^= 1;
                --ck;
            }
        }
        ures[lane] = u;                      // cols >= 48 never read
        if (lane == 0) shSB = SB;
    }

    __syncthreads();

    // ---- combine (wave 0): logZ = ln2 * (log2( sum_j z[j]*u[j] ) + SF + SB) ----
    if (wid == 0) {
        float prod = (lane < NC) ? z * ures[lane] : 0.f;
        #pragma unroll
        for (int k = 32; k >= 1; k >>= 1) prod += __shfl_xor(prod, k, 64);
        float logZ = (__builtin_amdgcn_logf(prod) + SF + shSB) * LN2;
        if (lane == 0) {
            float X = xpart[0] + xpart[1];
            out[b]         = X;          // output 0: X
            out[BATCH + b] = X - logZ;   // output 1: X - logZ
        }
    }
}

extern "C" void kernel_launch(void* const* d_in, const int* in_sizes, int n_in,
                              void* d_out, int out_size, void* d_ws, size_t ws_size,
                              hipStream_t stream) {
    const float* scores  = (const float*)d_in[0];
    const int*   target  = (const int*)d_in[1];
    const int*   lengths = (const int*)d_in[2];
    const float* trans   = (const float*)d_in[3];
    float* out = (float*)d_out;
    crf_fwd<<<BATCH, 128, 0, stream>>>(scores, target, lengths, trans, out);
}